// Round 6
// baseline (180.800 us; speedup 1.0000x reference)
//
#include <hip/hip_runtime.h>
#include <hip/hip_bf16.h>
#include <hip/hip_cooperative_groups.h>

namespace cg = cooperative_groups;

#define N_NODES 100000
#define N_EDGES 1600000
#define IN_DIM 128
#define HID 64
#define NB 391                 // buckets of 256 dst nodes
#define EPB 4096               // edges per bucket-phase chunk
#define MAXPB 8192             // fixed gbuf region per bucket (mean 4092)
#define AGGR_VB 3125           // aggr virtual blocks (32 dsts each) = 100000/32

typedef __attribute__((ext_vector_type(8))) short bf16x8;
typedef __attribute__((ext_vector_type(4))) float f32x4;

// ---------------- threefry2x32, key = (0, 42) ----------------
__device__ __forceinline__ unsigned rotl32(unsigned x, unsigned r) {
    return (x << r) | (x >> (32u - r));
}

__device__ __forceinline__ void threefry2x32_k42(unsigned x0, unsigned x1,
                                                 unsigned& o0, unsigned& o1) {
    const unsigned ks0 = 0u;
    const unsigned ks1 = 42u;
    const unsigned ks2 = 0u ^ 42u ^ 0x1BD11BDAu;
    x0 += ks0; x1 += ks1;
    x0 += x1; x1 = rotl32(x1, 13); x1 ^= x0;
    x0 += x1; x1 = rotl32(x1, 15); x1 ^= x0;
    x0 += x1; x1 = rotl32(x1, 26); x1 ^= x0;
    x0 += x1; x1 = rotl32(x1, 6);  x1 ^= x0;
    x0 += ks1; x1 += ks2 + 1u;
    x0 += x1; x1 = rotl32(x1, 17); x1 ^= x0;
    x0 += x1; x1 = rotl32(x1, 29); x1 ^= x0;
    x0 += x1; x1 = rotl32(x1, 16); x1 ^= x0;
    x0 += x1; x1 = rotl32(x1, 24); x1 ^= x0;
    x0 += ks2; x1 += ks0 + 2u;
    x0 += x1; x1 = rotl32(x1, 13); x1 ^= x0;
    x0 += x1; x1 = rotl32(x1, 15); x1 ^= x0;
    x0 += x1; x1 = rotl32(x1, 26); x1 ^= x0;
    x0 += x1; x1 = rotl32(x1, 6);  x1 ^= x0;
    x0 += ks0; x1 += ks1 + 3u;
    x0 += x1; x1 = rotl32(x1, 17); x1 ^= x0;
    x0 += x1; x1 = rotl32(x1, 29); x1 ^= x0;
    x0 += x1; x1 = rotl32(x1, 16); x1 ^= x0;
    x0 += x1; x1 = rotl32(x1, 24); x1 ^= x0;
    x0 += ks1; x1 += ks2 + 4u;
    x0 += x1; x1 = rotl32(x1, 13); x1 ^= x0;
    x0 += x1; x1 = rotl32(x1, 15); x1 ^= x0;
    x0 += x1; x1 = rotl32(x1, 26); x1 ^= x0;
    x0 += x1; x1 = rotl32(x1, 6);  x1 ^= x0;
    x0 += ks2; x1 += ks0 + 5u;
    o0 = x0; o1 = x1;
}

__device__ __forceinline__ float bf2f(unsigned short u) {
    return __uint_as_float((unsigned)u << 16);
}
__device__ __forceinline__ float bf2f_lo(unsigned u) {
    return __uint_as_float(u << 16);
}
__device__ __forceinline__ float bf2f_hi(unsigned u) {
    return __uint_as_float(u & 0xffff0000u);
}
__device__ __forceinline__ uint2 loadg(const unsigned short* __restrict__ gm, int ri, int d4) {
    return *(const uint2*)(gm + ((size_t)ri << 6) + (d4 << 2));
}

// ---------------- LDS phase structs (union'd in fused kernels) ----------------
struct LdsP1 {            // bucket phase: 31.1 KB
    int cnt[512]; int off[512]; int cur[NB]; int gbase[NB];
    unsigned buf[EPB]; unsigned short bkt[EPB];
};
struct LdsP2 {            // csr phase: 35.8 KB
    unsigned lbuf[MAXPB]; int lcnt[256]; int pre[256]; int cur[256];
};
struct LdsP3 {            // gemm phase: 34.8 KB
    unsigned short WtH[HID][136]; unsigned short WtL[HID][136];
};
union LdsAll { LdsP1 p1; LdsP2 p2; LdsP3 p3; };
union LdsCG  { LdsP2 p2; LdsP3 p3; };

// ---- phase 1: bucketed scatter into FIXED regions (r5 logic, 512 thr) ----
// record = (c & 255) << 17 | r   (r < 2^17)
__device__ __forceinline__ void phase_bucket(int chunk, const int* __restrict__ src,
                                             const int* __restrict__ dst,
                                             int* __restrict__ bucketcnt,
                                             unsigned* __restrict__ gbuf, LdsP1& L) {
    const int t = threadIdx.x;
    const int e0 = chunk * EPB;
    const int n = min(EPB, N_EDGES - e0);
    L.cnt[t] = 0;
    __syncthreads();
    unsigned myrec[EPB / 512];
    int myb[EPB / 512];
#pragma unroll
    for (int k = 0; k < EPB / 512; k++) {
        int e = e0 + k * 512 + t;
        if (e < N_EDGES) {
            int r = src[e];
            int c = dst[e];
            int b = c >> 8;
            myrec[k] = ((unsigned)(c & 255) << 17) | (unsigned)r;
            myb[k] = b;
            atomicAdd(&L.cnt[b], 1);
        } else {
            myb[k] = -1;
        }
    }
    __syncthreads();
    int own = L.cnt[t];
    for (int o = 1; o < 512; o <<= 1) {
        int v = (t >= o) ? L.cnt[t - o] : 0;
        __syncthreads();
        L.cnt[t] += v;
        __syncthreads();
    }
    L.off[t] = L.cnt[t] - own;
    if (t < NB) {
        L.cur[t] = L.off[t];
        L.gbase[t] = t * MAXPB + (own ? atomicAdd(&bucketcnt[t], own) : 0);
    }
    __syncthreads();
#pragma unroll
    for (int k = 0; k < EPB / 512; k++) {
        if (myb[k] >= 0) {
            int p = atomicAdd(&L.cur[myb[k]], 1);
            L.buf[p] = myrec[k];
            L.bkt[p] = (unsigned short)myb[k];
        }
    }
    __syncthreads();
    for (int j = t; j < n; j += 512) {
        int b = L.bkt[j];
        gbuf[L.gbase[b] + (j - L.off[b])] = L.buf[j];
    }
    __syncthreads();  // drain before next grid-stride iteration reuses L
}

// ---- phase 2a: per-bucket count+scan -> row_se/dinv(+LDS), in-place srcs ----
__device__ __forceinline__ void phase_csr(int b, unsigned* __restrict__ gbuf,
                                          const int* __restrict__ bucketcnt,
                                          int2* __restrict__ row_se,
                                          float* __restrict__ dinv,
                                          float* __restrict__ dinvL, LdsP2& L) {
    const int t = threadIdx.x;
    const int n = bucketcnt[b];
    const unsigned* reg = gbuf + (size_t)b * MAXPB;
    __syncthreads();  // protect union reuse (previous phase's LDS reads done)
    if (t < 256) L.lcnt[t] = 0;
    for (int j = t; j < n; j += 512) L.lbuf[j] = reg[j];
    __syncthreads();
    for (int j = t; j < n; j += 512) atomicAdd(&L.lcnt[L.lbuf[j] >> 17], 1);
    __syncthreads();
    int my = 0;
    if (t < 256) { my = L.lcnt[t]; L.pre[t] = my; }
    __syncthreads();
    for (int o = 1; o < 256; o <<= 1) {
        int v = 0;
        if (t < 256 && t >= o) v = L.pre[t - o];
        __syncthreads();
        if (t < 256) L.pre[t] += v;
        __syncthreads();
    }
    if (t < 256) {
        const int base = b * MAXPB + L.pre[t] - my;  // absolute pos in gbuf
        L.cur[t] = base;
        const float dv = rsqrtf((float)(my + 1));    // in-degree + self-loop
        dinvL[t] = dv;
        const int c = b * 256 + t;
        if (c < N_NODES) {
            row_se[c] = make_int2(base, base + my);
            dinv[c] = dv;
        }
    }
    __syncthreads();
    // all records safe in lbuf; overwrite the region with src ids
    for (int j = t; j < n; j += 512) {
        const unsigned rec = L.lbuf[j];
        const int pos = atomicAdd(&L.cur[rec >> 17], 1);
        ((int*)gbuf)[pos] = (int)(rec & 0x1FFFF);
    }
}

// ---- phase 2b: MFMA split-bf16 GEMM for rows [b*256, b*256+256) ----
// dinv comes from dinvL (this block's csr phase) — same-block dependency.
__device__ __forceinline__ void phase_gemm(int b, const float* __restrict__ x,
                                           const float* __restrict__ W,
                                           unsigned short* __restrict__ gm,
                                           const float* __restrict__ dinvL, LdsP3& L) {
    const int t = threadIdx.x;
    __syncthreads();  // protect union reuse (csr's lbuf reads done)
    {
        const int nn = t & 63;
        const int k0 = (t >> 6) * 16;
        for (int k = k0; k < k0 + 16; k += 2) {
            float w0 = W[(size_t)k * HID + nn];
            float w1 = W[(size_t)(k + 1) * HID + nn];
            unsigned short h0 = __bfloat16_as_ushort(__float2bfloat16(w0));
            unsigned short h1 = __bfloat16_as_ushort(__float2bfloat16(w1));
            unsigned short l0 = __bfloat16_as_ushort(__float2bfloat16(w0 - bf2f(h0)));
            unsigned short l1 = __bfloat16_as_ushort(__float2bfloat16(w1 - bf2f(h1)));
            *(unsigned*)&L.WtH[nn][k] = (unsigned)h0 | ((unsigned)h1 << 16);
            *(unsigned*)&L.WtL[nn][k] = (unsigned)l0 | ((unsigned)l1 << 16);
        }
    }
    __syncthreads();
    const int wave = t >> 6, lane = t & 63;
    const int row16 = lane & 15;
    const int kgrp = lane >> 4;
#pragma unroll
    for (int p = 0; p < 2; p++) {
        const int browA = b * 256 + p * 128 + wave * 16;
        const int rA = min(browA + row16, N_NODES - 1);
        const float* xr = x + (size_t)rA * IN_DIM + kgrp * 8;
        float xv[32];
#pragma unroll
        for (int ks = 0; ks < 4; ks++) {
            *(f32x4*)&xv[ks * 8]     = *(const f32x4*)(xr + ks * 32);
            *(f32x4*)&xv[ks * 8 + 4] = *(const f32x4*)(xr + ks * 32 + 4);
        }
        bf16x8 ah[4], al[4];
#pragma unroll
        for (int ks = 0; ks < 4; ks++) {
#pragma unroll
            for (int j = 0; j < 8; j++) {
                float v = xv[ks * 8 + j];
                unsigned short h = __bfloat16_as_ushort(__float2bfloat16(v));
                unsigned short l = __bfloat16_as_ushort(__float2bfloat16(v - bf2f(h)));
                ah[ks][j] = (short)h;
                al[ks][j] = (short)l;
            }
        }
        float dv[4];
        int orow[4];
#pragma unroll
        for (int i = 0; i < 4; i++) {
            orow[i] = browA + kgrp * 4 + i;
            dv[i] = dinvL[p * 128 + wave * 16 + kgrp * 4 + i];
        }
#pragma unroll
        for (int nt = 0; nt < 4; nt++) {
            const int nn = nt * 16 + row16;
            bf16x8 bh[4], bl[4];
#pragma unroll
            for (int ks = 0; ks < 4; ks++) {
                bh[ks] = *(const bf16x8*)&L.WtH[nn][ks * 32 + kgrp * 8];
                bl[ks] = *(const bf16x8*)&L.WtL[nn][ks * 32 + kgrp * 8];
            }
            f32x4 acc = {0.f, 0.f, 0.f, 0.f};
#pragma unroll
            for (int ks = 0; ks < 4; ks++)
                acc = __builtin_amdgcn_mfma_f32_16x16x32_bf16(ah[ks], bh[ks], acc, 0, 0, 0);
#pragma unroll
            for (int ks = 0; ks < 4; ks++)
                acc = __builtin_amdgcn_mfma_f32_16x16x32_bf16(al[ks], bh[ks], acc, 0, 0, 0);
#pragma unroll
            for (int ks = 0; ks < 4; ks++)
                acc = __builtin_amdgcn_mfma_f32_16x16x32_bf16(ah[ks], bl[ks], acc, 0, 0, 0);
#pragma unroll
            for (int i = 0; i < 4; i++) {
                if (orow[i] < N_NODES) {
                    float g = acc[i] * dv[i];
                    gm[(size_t)orow[i] * HID + nt * 16 + row16] =
                        __bfloat16_as_ushort(__float2bfloat16(g));
                }
            }
        }
    }
}

// ---- phase 3: gather + self + bias/relu/dropout + [64->2] matvec ----
// 512 thr = 32 dsts per virtual block, 16 lanes/dst, masked 8-batch ping-pong.
__device__ __forceinline__ void phase_aggr(int vb, const unsigned short* __restrict__ gm,
                                           const int2* __restrict__ row_se,
                                           const int* __restrict__ srcs,
                                           const float* __restrict__ dinv,
                                           const float* __restrict__ bconv,
                                           const float* __restrict__ Wlin,
                                           const float* __restrict__ blin,
                                           float* __restrict__ out) {
    const int t = threadIdx.x;
    const int c  = vb * 32 + (t >> 4);
    const int d4 = t & 15;
    const int2 se = row_se[c];
    const int beg = se.x;
    const int end = se.y;

    const uint2 s0 = loadg(gm, c, d4);
    float a0 = bf2f_lo(s0.x), a1 = bf2f_hi(s0.x);
    float a2 = bf2f_lo(s0.y), a3 = bf2f_hi(s0.y);

    if (beg < end) {
        const int last = end - 1;
        int r[8];
        uint2 wa[8], wb[8];
#pragma unroll
        for (int u = 0; u < 8; u++) r[u] = srcs[min(beg + u, last)];
#pragma unroll
        for (int u = 0; u < 8; u++) wa[u] = loadg(gm, r[u], d4);
        bool haveB = (beg + 8 < end);
        if (haveB) {
#pragma unroll
            for (int u = 0; u < 8; u++) r[u] = srcs[min(beg + 8 + u, last)];
#pragma unroll
            for (int u = 0; u < 8; u++) wb[u] = loadg(gm, r[u], d4);
        }
        int j = beg;
        while (true) {
#pragma unroll
            for (int u = 0; u < 8; u++) {
                const unsigned m = (j + u < end) ? 0xffffffffu : 0u;
                a0 += bf2f_lo(wa[u].x & m); a1 += bf2f_hi(wa[u].x & m);
                a2 += bf2f_lo(wa[u].y & m); a3 += bf2f_hi(wa[u].y & m);
            }
            j += 8;
            if (!haveB) break;
            const bool haveN = (j + 8 < end);
            if (haveN) {
#pragma unroll
                for (int u = 0; u < 8; u++) r[u] = srcs[min(j + 8 + u, last)];
#pragma unroll
                for (int u = 0; u < 8; u++) wa[u] = loadg(gm, r[u], d4);
            }
#pragma unroll
            for (int u = 0; u < 8; u++) {
                const unsigned m = (j + u < end) ? 0xffffffffu : 0u;
                a0 += bf2f_lo(wb[u].x & m); a1 += bf2f_hi(wb[u].x & m);
                a2 += bf2f_lo(wb[u].y & m); a3 += bf2f_hi(wb[u].y & m);
            }
            j += 8;
            if (!haveN) break;
            haveB = (j + 8 < end);
            if (haveB) {
#pragma unroll
                for (int u = 0; u < 8; u++) r[u] = srcs[min(j + 8 + u, last)];
#pragma unroll
                for (int u = 0; u < 8; u++) wb[u] = loadg(gm, r[u], d4);
            }
        }
    }

    const float dv = dinv[c];
    const float4 bc4 = *(const float4*)(bconv + (d4 << 2));
    float v0 = fmaxf(a0 * dv + bc4.x, 0.f);
    float v1 = fmaxf(a1 * dv + bc4.y, 0.f);
    float v2 = fmaxf(a2 * dv + bc4.z, 0.f);
    float v3 = fmaxf(a3 * dv + bc4.w, 0.f);

    const unsigned ib = (unsigned)(c * HID + (d4 << 2));
    unsigned o0, o1;
    threefry2x32_k42(0u, ib + 0u, o0, o1);
    v0 = ((o0 ^ o1) & 0x80000000u) ? 0.f : v0 * 2.f;
    threefry2x32_k42(0u, ib + 1u, o0, o1);
    v1 = ((o0 ^ o1) & 0x80000000u) ? 0.f : v1 * 2.f;
    threefry2x32_k42(0u, ib + 2u, o0, o1);
    v2 = ((o0 ^ o1) & 0x80000000u) ? 0.f : v2 * 2.f;
    threefry2x32_k42(0u, ib + 3u, o0, o1);
    v3 = ((o0 ^ o1) & 0x80000000u) ? 0.f : v3 * 2.f;

    const float4 wl0 = *(const float4*)(Wlin + (d4 << 3));
    const float4 wl1 = *(const float4*)(Wlin + (d4 << 3) + 4);
    float p0 = v0 * wl0.x + v1 * wl0.z + v2 * wl1.x + v3 * wl1.z;
    float p1 = v0 * wl0.y + v1 * wl0.w + v2 * wl1.y + v3 * wl1.w;

#pragma unroll
    for (int off = 8; off; off >>= 1) {
        p0 += __shfl_xor(p0, off);
        p1 += __shfl_xor(p1, off);
    }
    if (d4 == 0) {
        *(float2*)(out + (size_t)c * 2) = make_float2(p0 + blin[0], p1 + blin[1]);
    }
}

// ---------------- cooperative all-in-one kernel ----------------
__global__ void __launch_bounds__(512) k_all(const int* __restrict__ src,
                                             const int* __restrict__ dst,
                                             int* __restrict__ bucketcnt,
                                             unsigned* __restrict__ gbuf,
                                             const float* __restrict__ x,
                                             const float* __restrict__ W,
                                             unsigned short* __restrict__ gm,
                                             int2* __restrict__ row_se,
                                             float* __restrict__ dinv,
                                             const float* __restrict__ bconv,
                                             const float* __restrict__ Wlin,
                                             const float* __restrict__ blin,
                                             float* __restrict__ out) {
    __shared__ LdsAll sh;
    __shared__ float dinvL[256];
    const int G = gridDim.x;
    for (int chunk = blockIdx.x; chunk < NB; chunk += G)
        phase_bucket(chunk, src, dst, bucketcnt, gbuf, sh.p1);
    __threadfence();
    cg::this_grid().sync();
    for (int b = blockIdx.x; b < NB; b += G) {
        phase_csr(b, gbuf, bucketcnt, row_se, dinv, dinvL, sh.p2);
        phase_gemm(b, x, W, gm, dinvL, sh.p3);
    }
    __threadfence();
    cg::this_grid().sync();
    for (int vb = blockIdx.x; vb < AGGR_VB; vb += G)
        phase_aggr(vb, gm, row_se, (const int*)gbuf, dinv, bconv, Wlin, blin, out);
}

// ---------------- fallback kernels (same phase code, separate dispatches) ----------------
__global__ void __launch_bounds__(512) k_bucketF(const int* __restrict__ src,
                                                 const int* __restrict__ dst,
                                                 int* __restrict__ bucketcnt,
                                                 unsigned* __restrict__ gbuf) {
    __shared__ LdsP1 sh;
    phase_bucket(blockIdx.x, src, dst, bucketcnt, gbuf, sh);
}

__global__ void __launch_bounds__(512) k_csrgemmF(unsigned* __restrict__ gbuf,
                                                  const int* __restrict__ bucketcnt,
                                                  int2* __restrict__ row_se,
                                                  float* __restrict__ dinv,
                                                  const float* __restrict__ x,
                                                  const float* __restrict__ W,
                                                  unsigned short* __restrict__ gm) {
    __shared__ LdsCG sh;
    __shared__ float dinvL[256];
    phase_csr(blockIdx.x, gbuf, bucketcnt, row_se, dinv, dinvL, sh.p2);
    phase_gemm(blockIdx.x, x, W, gm, dinvL, sh.p3);
}

__global__ void __launch_bounds__(512) k_aggrF(const unsigned short* __restrict__ gm,
                                               const int2* __restrict__ row_se,
                                               const int* __restrict__ srcs,
                                               const float* __restrict__ dinv,
                                               const float* __restrict__ bconv,
                                               const float* __restrict__ Wlin,
                                               const float* __restrict__ blin,
                                               float* __restrict__ out) {
    phase_aggr(blockIdx.x, gm, row_se, srcs, dinv, bconv, Wlin, blin, out);
}

extern "C" void kernel_launch(void* const* d_in, const int* in_sizes, int n_in,
                              void* d_out, int out_size, void* d_ws, size_t ws_size,
                              hipStream_t stream) {
    // Map inputs BY ELEMENT COUNT (all unique) — robust to positional order.
    const float* x  = (const float*)d_in[0];
    const void*  ei = d_in[1];
    const float* Wc = (const float*)d_in[2];
    const float* bc = (const float*)d_in[3];
    const float* Wl = (const float*)d_in[4];
    const float* bl = (const float*)d_in[5];
    for (int i = 0; i < n_in; i++) {
        switch (in_sizes[i]) {
            case N_NODES * IN_DIM:   x  = (const float*)d_in[i]; break;
            case 2 * N_EDGES:
            case 4 * N_EDGES:        ei = d_in[i]; break;
            case IN_DIM * HID:       Wc = (const float*)d_in[i]; break;
            case HID:                bc = (const float*)d_in[i]; break;
            case HID * 2:            Wl = (const float*)d_in[i]; break;
            case 2:                  bl = (const float*)d_in[i]; break;
            default: break;
        }
    }
    float* out = (float*)d_out;

    const int* src = (const int*)ei;            // edge_index[0] (int32, proven r2≡r3)
    const int* dst = (const int*)ei + N_EDGES;  // edge_index[1]

    char* ws = (char*)d_ws;
    size_t off = 0;
    unsigned short* gm = (unsigned short*)(ws + off); off += (size_t)N_NODES * HID * 2;  // 12.8 MB
    float* dinv        = (float*)(ws + off);   off += (size_t)N_NODES * 4;               // 0.4 MB
    int2*  row_se      = (int2*)(ws + off);    off += (size_t)N_NODES * 8;               // 0.8 MB
    int*   bucketcnt   = (int*)(ws + off);     off += (size_t)(NB + 64) * 4;
    off = (off + 255) & ~(size_t)255;
    unsigned* gbuf     = (unsigned*)(ws + off); off += (size_t)NB * MAXPB * 4;           // 12.8 MB
    // gbuf doubles as srcs (records overwritten in place by the csr phase)

    hipMemsetAsync(bucketcnt, 0, (size_t)NB * 4, stream);

    // Cooperative path: grid sized to co-residency (grid-stride phases tolerate
    // any grid >= 1). Cached across calls; on any failure fall back permanently.
    static int coop_grid = -2;
    if (coop_grid == -2) {
        int occ = 0;
        if (hipOccupancyMaxActiveBlocksPerMultiprocessor(&occ, k_all, 512, 0) == hipSuccess
            && occ > 0) {
            int g = occ * 256;           // 256 CUs on MI355X
            coop_grid = g < NB ? g : NB;
        } else {
            coop_grid = -1;
        }
    }
    bool done = false;
    if (coop_grid > 0) {
        void* args[] = {(void*)&src, (void*)&dst, (void*)&bucketcnt, (void*)&gbuf,
                        (void*)&x, (void*)&Wc, (void*)&gm, (void*)&row_se,
                        (void*)&dinv, (void*)&bc, (void*)&Wl, (void*)&bl, (void*)&out};
        if (hipLaunchCooperativeKernel(k_all, dim3(coop_grid), dim3(512),
                                       args, 0, stream) == hipSuccess) {
            done = true;
        } else {
            (void)hipGetLastError();
            coop_grid = -1;
        }
    }
    if (!done) {
        k_bucketF<<<NB, 512, 0, stream>>>(src, dst, bucketcnt, gbuf);
        k_csrgemmF<<<NB, 512, 0, stream>>>(gbuf, bucketcnt, row_se, dinv, x, Wc, gm);
        k_aggrF<<<AGGR_VB, 512, 0, stream>>>(gm, row_se, (const int*)gbuf,
                                             dinv, bc, Wl, bl, out);
    }
}